// Round 13
// baseline (251.276 us; speedup 1.0000x reference)
//
#include <hip/hip_runtime.h>
#include <math.h>

constexpr float NEG_SLOPE = 0.2f;
constexpr float LN_EPS = 1e-5f;

typedef __attribute__((ext_vector_type(8))) short short8;   // bf16x8 MFMA frag
typedef __attribute__((ext_vector_type(4))) float f32x4;    // MFMA acc
typedef __attribute__((ext_vector_type(2))) float f32x2;

__device__ inline ushort f2bf(float f) {        // fp32 -> bf16 RTN-even
    uint u = __float_as_uint(f);
    u += 0x7fffu + ((u >> 16) & 1u);
    return (ushort)(u >> 16);
}

__device__ inline float pick4(float4 v, int h) {
    float r = v.x;
    r = (h == 1) ? v.y : r;
    r = (h == 2) ? v.z : r;
    r = (h == 3) ? v.w : r;
    return r;
}

// fp8 e4m3 (OCP) encode/decode via gfx950 HW converters
__device__ inline uchar f2q(float v) {
    int r = __builtin_amdgcn_cvt_pk_fp8_f32(v, v, 0, false);
    return (uchar)(r & 0xff);
}

// packed: 4x v_pk_fma_f32 + 4x cvt_pk per edge (8 channels)
__device__ inline void fma8q(const uint2& u, float q, f32x2 acc[4]) {
    f32x2 qq = {q, q};
    acc[0] += qq * __builtin_amdgcn_cvt_pk_f32_fp8(u.x, false);
    acc[1] += qq * __builtin_amdgcn_cvt_pk_f32_fp8(u.x, true);
    acc[2] += qq * __builtin_amdgcn_cvt_pk_f32_fp8(u.y, false);
    acc[3] += qq * __builtin_amdgcn_cvt_pk_f32_fp8(u.y, true);
}

// ---------------- fused pre-pass: dtype conversions + window counts --------

__global__ __launch_bounds__(256) void k_pre(
    const float* __restrict__ x,
    const float* __restrict__ W0,
    const float* __restrict__ W1,
    const int* __restrict__ ei,
    ushort* __restrict__ Xb,
    ushort* __restrict__ Wt0,
    ushort* __restrict__ Wt1,
    int* __restrict__ wcnt, int N, int E) {
    __shared__ int lcnt[256];
    lcnt[threadIdx.x] = 0;
    __syncthreads();

    int i = blockIdx.x * blockDim.x + threadIdx.x;
    const int nx = N * 8;
    if (i < nx) {
        float4 a = *reinterpret_cast<const float4*>(x + (size_t)i * 8);
        float4 b = *reinterpret_cast<const float4*>(x + (size_t)i * 8 + 4);
        ushort u[8] = {f2bf(a.x), f2bf(a.y), f2bf(a.z), f2bf(a.w),
                       f2bf(b.x), f2bf(b.y), f2bf(b.z), f2bf(b.w)};
        *reinterpret_cast<uint4*>(Xb + (size_t)i * 8) = *reinterpret_cast<const uint4*>(u);
    } else {
        int j = i - nx;
        if (j < 64 * 256) {
            int k = j >> 8, c = j & 255;
            Wt0[(size_t)c * 64 + k] = f2bf(W0[j]);
        } else {
            j -= 64 * 256;
            if (j < 256 * 256) {
                int k = j >> 8, c = j & 255;
                Wt1[(size_t)c * 256 + k] = f2bf(W1[j]);
            } else {
                j -= 256 * 256;
                if (j < E + N) {
                    int dst = (j < E) ? ei[E + j] : (j - E);
                    atomicAdd(&lcnt[dst >> 8], 1);
                }
            }
        }
    }
    __syncthreads();
    int c = lcnt[threadIdx.x];
    if (c) atomicAdd(&wcnt[threadIdx.x], c);
}

// ---------------- CSR build: window-local, no global per-node atomics -------

// exclusive scan of window counts (nbw <= 256); wcur gets 64B-strided copy
__global__ __launch_bounds__(256) void k_winscan(const int* __restrict__ wcnt,
                                                 int* __restrict__ wbase,
                                                 int* __restrict__ wcur, int nbw) {
    __shared__ int buf[256];
    const int t = threadIdx.x;
    int v = (t < nbw) ? wcnt[t] : 0;
    buf[t] = v;
    __syncthreads();
    for (int off = 1; off < 256; off <<= 1) {
        int a = (t >= off) ? buf[t - off] : 0;
        __syncthreads();
        buf[t] += a;
        __syncthreads();
    }
    int excl = buf[t] - v;
    if (t < nbw) { wbase[t] = excl; wcur[t * 16] = excl; }
}

// bin edges into per-window contiguous tmp regions (block-agg reservation)
__global__ __launch_bounds__(1024) void k_binA(const int* __restrict__ ei, int E, int N,
                                               int nbw, int* __restrict__ wcur,
                                               unsigned long long* __restrict__ tmp) {
    __shared__ int lcnt[256];
    __shared__ int lbase[256];
    const int tid = threadIdx.x;
    if (tid < 256) lcnt[tid] = 0;
    __syncthreads();
    int i = blockIdx.x * 1024 + tid;
    int src = 0, dst = 0, rank = 0, buc = 0;
    const bool valid = i < E + N;
    if (valid) {
        if (i < E) { src = ei[i]; dst = ei[E + i]; }
        else       { src = i - E; dst = i - E; }
        buc = dst >> 8;
        rank = atomicAdd(&lcnt[buc], 1);          // LDS atomic
    }
    __syncthreads();
    if (tid < 256) {
        int c = lcnt[tid];
        lbase[tid] = c ? atomicAdd(&wcur[tid * 16], c) : 0;
    }
    __syncthreads();
    if (valid)
        tmp[lbase[buc] + rank] = ((unsigned long long)(uint)dst << 32) | (uint)src;
}

// per-window: LDS histogram + scan -> offs; LDS-atomic scatter -> csr
__global__ __launch_bounds__(256) void k_win(const unsigned long long* __restrict__ tmp,
                                             const int* __restrict__ wbase,
                                             const int* __restrict__ wcnt,
                                             int nbw, int N,
                                             int* __restrict__ offs,
                                             int* __restrict__ csr) {
    __shared__ int hist[256];
    __shared__ int cur[256];
    __shared__ int buf[256];
    const int w = blockIdx.x;
    const int t = threadIdx.x;
    const int base = wbase[w];
    const int count = wcnt[w];

    hist[t] = 0;
    __syncthreads();
    for (int i = t; i < count; i += 256) {
        int dst = (int)(tmp[base + i] >> 32);
        atomicAdd(&hist[dst & 255], 1);
    }
    __syncthreads();
    int v = hist[t];
    buf[t] = v;
    __syncthreads();
    for (int off = 1; off < 256; off <<= 1) {
        int a = (t >= off) ? buf[t - off] : 0;
        __syncthreads();
        buf[t] += a;
        __syncthreads();
    }
    int excl = buf[t] - v;
    cur[t] = excl;
    int node = w * 256 + t;
    if (node < N) offs[node] = base + excl;
    if (t == 0 && w == nbw - 1) offs[N] = base + count;
    __syncthreads();
    for (int i = t; i < count; i += 256) {
        unsigned long long e = tmp[base + i];
        int dst = (int)(e >> 32);
        int src = (int)(e & 0xffffffffu);
        int pos = base + atomicAdd(&cur[dst & 255], 1);
        csr[pos] = src;
    }
}

// ---------------- MFMA GEMM: h = Xb * W  (+ fused s,t scores) ----------------
// Xb: [N][K] bf16, Wt: [256][K] bf16, h: [N][256] fp8-e4m3, s,t: [N][4] fp32.

template <int K>
__global__ __launch_bounds__(256, 2) void k_gemm_mfma(
    const ushort* __restrict__ Xb, const ushort* __restrict__ Wt,
    const float* __restrict__ a_s, const float* __restrict__ a_d,
    uchar* __restrict__ h, float* __restrict__ s, float* __restrict__ t,
    int N, int nrb, int cpx, int rbpc)
{
    constexpr int KC = K / 32;
    __shared__ uchar hstage[4][16][72];    // fp8, padded row stride 72B

    const int tid = threadIdx.x;
    const int w = tid >> 6;
    const int l = tid & 63;
    const int lr = l & 15;
    const int lk = l >> 4;

    const int bid = blockIdx.x;
    const int xcd = bid & 7;
    const int j = bid >> 3;
    const int slice = j & 3;
    const int chunk = xcd * cpx + (j >> 2);
    const int rb0 = chunk * rbpc;
    const int rb1 = min(rb0 + rbpc, nrb);

    short8 b[4][KC];
#pragma unroll
    for (int ct = 0; ct < 4; ++ct) {
        const ushort* wp = Wt + (size_t)(slice * 64 + ct * 16 + lr) * K + lk * 8;
#pragma unroll
        for (int kc = 0; kc < KC; ++kc)
            b[ct][kc] = *reinterpret_cast<const short8*>(wp + kc * 32);
    }

    float asv[4], adv[4];
#pragma unroll
    for (int ct = 0; ct < 4; ++ct) {
        asv[ct] = a_s[slice * 64 + ct * 16 + lr];
        adv[ct] = a_d[slice * 64 + ct * 16 + lr];
    }

    for (int rb = rb0; rb < rb1; ++rb) {
        const int row0 = rb * 64 + w * 16;

        int arow = row0 + lr;
        arow = (arow < N) ? arow : (N - 1);
        const ushort* xp = Xb + (size_t)arow * K + lk * 8;
        short8 a[KC];
#pragma unroll
        for (int kc = 0; kc < KC; ++kc)
            a[kc] = *reinterpret_cast<const short8*>(xp + kc * 32);

        f32x4 acc[4];
#pragma unroll
        for (int ct = 0; ct < 4; ++ct) acc[ct] = (f32x4){0.f, 0.f, 0.f, 0.f};
#pragma unroll
        for (int ct = 0; ct < 4; ++ct)
#pragma unroll
            for (int kc = 0; kc < KC; ++kc)
                acc[ct] = __builtin_amdgcn_mfma_f32_16x16x32_bf16(a[kc], b[ct][kc], acc[ct], 0, 0, 0);

        // fused s,t scores (fp32)
        float ps[4] = {0.f, 0.f, 0.f, 0.f}, pt[4] = {0.f, 0.f, 0.f, 0.f};
#pragma unroll
        for (int jj = 0; jj < 4; ++jj) {
#pragma unroll
            for (int ct = 0; ct < 4; ++ct) {
                float v = acc[ct][jj];
                ps[jj] = fmaf(v, asv[ct], ps[jj]);
                pt[jj] = fmaf(v, adv[ct], pt[jj]);
            }
        }
#pragma unroll
        for (int jj = 0; jj < 4; ++jj) {
#pragma unroll
            for (int o = 1; o < 16; o <<= 1) {
                ps[jj] += __shfl_xor(ps[jj], o);
                pt[jj] += __shfl_xor(pt[jj], o);
            }
        }
        if (lr == 0) {
#pragma unroll
            for (int jj = 0; jj < 4; ++jj) {
                int row = row0 + lk * 4 + jj;
                if (row < N) {
                    s[(size_t)row * 4 + slice] = ps[jj];
                    t[(size_t)row * 4 + slice] = pt[jj];
                }
            }
        }

        // stage fp8 tile in LDS (per-wave private), store 64B row-chunks
#pragma unroll
        for (int ct = 0; ct < 4; ++ct)
#pragma unroll
            for (int jj = 0; jj < 4; ++jj)
                hstage[w][lk * 4 + jj][ct * 16 + lr] = f2q(acc[ct][jj]);
#pragma unroll
        for (int hf = 0; hf < 2; ++hf) {
            int r = (l >> 3) + hf * 8;      // 0..15
            int ch = l & 7;                 // 8B chunk within 64 cols
            int grow = rb * 64 + w * 16 + r;
            uint2 v = *reinterpret_cast<const uint2*>(&hstage[w][r][ch * 8]);
            if (grow < N)
                *reinterpret_cast<uint2*>(h + (size_t)grow * 256 + slice * 64 + ch * 8) = v;
        }
    }
}

// ---------------- aggregation (+ bias + LayerNorm + ELU) ----------------
// TWO nodes per wave: 32 lanes per node, lane owns 8 channels (8B fp8).
// Online softmax per 32-edge chunk; packed f32x2 accumulation (v_pk_fma_f32).

template <bool FUSE_W2>
__global__ __launch_bounds__(256) void k_agg_ln_elu(
    const int* __restrict__ offs, const int* __restrict__ csr,
    const float* __restrict__ s, const float* __restrict__ t,
    const uchar* __restrict__ h, const float* __restrict__ bias,
    const float* __restrict__ lng, const float* __restrict__ lnb,
    ushort* __restrict__ Y, const float* __restrict__ W2,
    float* __restrict__ h2, int N)
{
    __shared__ float p_s[4][2][32][4];
    __shared__ int off_s[4][2][32];

    const int tid = threadIdx.x;
    const int wid = tid >> 6;
    const int lane = tid & 63;
    const int half = lane >> 5;
    const int lh = lane & 31;
    const int n = blockIdx.x * 8 + wid * 2 + half;
    if (n >= N) return;
    const int head = lh >> 3;
    const int c0 = lh * 8;

    const float4 t4 = *reinterpret_cast<const float4*>(t + (size_t)n * 4);
    const int beg = offs[n], end = offs[n + 1];

    float4 m4 = make_float4(-1e30f, -1e30f, -1e30f, -1e30f);
    float4 den4 = make_float4(0.f, 0.f, 0.f, 0.f);
    f32x2 acc2[4];
#pragma unroll
    for (int c = 0; c < 4; ++c) acc2[c] = (f32x2){0.f, 0.f};

    const uchar* hb = h + lh * 8;
    float* pp = &p_s[wid][half][0][0];
    int* op = &off_s[wid][half][0];

    for (int base = beg; base < end; base += 32) {
        const int cnt = min(32, end - base);
        int src = 0;
        float4 e4 = make_float4(-1e30f, -1e30f, -1e30f, -1e30f);
        if (lh < cnt) {
            src = csr[base + lh];
            float4 sv = *reinterpret_cast<const float4*>(s + (size_t)src * 4);
            float ex = sv.x + t4.x, ey = sv.y + t4.y, ez = sv.z + t4.z, ew = sv.w + t4.w;
            e4.x = fmaxf(ex, NEG_SLOPE * ex);
            e4.y = fmaxf(ey, NEG_SLOPE * ey);
            e4.z = fmaxf(ez, NEG_SLOPE * ez);
            e4.w = fmaxf(ew, NEG_SLOPE * ew);
        }
        float4 bm = e4;
#pragma unroll
        for (int off = 1; off < 32; off <<= 1) {
            bm.x = fmaxf(bm.x, __shfl_xor(bm.x, off));
            bm.y = fmaxf(bm.y, __shfl_xor(bm.y, off));
            bm.z = fmaxf(bm.z, __shfl_xor(bm.z, off));
            bm.w = fmaxf(bm.w, __shfl_xor(bm.w, off));
        }
        float4 newm = make_float4(fmaxf(m4.x, bm.x), fmaxf(m4.y, bm.y),
                                  fmaxf(m4.z, bm.z), fmaxf(m4.w, bm.w));
        float4 sc4 = make_float4(__expf(m4.x - newm.x), __expf(m4.y - newm.y),
                                 __expf(m4.z - newm.z), __expf(m4.w - newm.w));
        m4 = newm;
        float sch = pick4(sc4, head);
        f32x2 sch2 = {sch, sch};
#pragma unroll
        for (int c = 0; c < 4; ++c) acc2[c] *= sch2;
        float4 p4 = make_float4(__expf(e4.x - newm.x), __expf(e4.y - newm.y),
                                __expf(e4.z - newm.z), __expf(e4.w - newm.w));
        den4.x = den4.x * sc4.x + p4.x;
        den4.y = den4.y * sc4.y + p4.y;
        den4.z = den4.z * sc4.z + p4.z;
        den4.w = den4.w * sc4.w + p4.w;

        *reinterpret_cast<float4*>(&p_s[wid][half][lh][0]) = p4;
        op[lh] = src << 8;              // byte offset of fp8 h row
        asm volatile("s_waitcnt lgkmcnt(0)" ::: "memory");

        // padded gather, 4 edges per iteration (pad entries have p == 0)
        for (int j0 = 0; j0 < cnt; j0 += 4) {
            int o0 = op[j0 + 0];
            int o1 = op[j0 + 1];
            int o2 = op[j0 + 2];
            int o3 = op[j0 + 3];
            float q0 = pp[(j0 + 0) * 4 + head];
            float q1 = pp[(j0 + 1) * 4 + head];
            float q2 = pp[(j0 + 2) * 4 + head];
            float q3 = pp[(j0 + 3) * 4 + head];
            uint2 u0 = *reinterpret_cast<const uint2*>(hb + o0);
            uint2 u1 = *reinterpret_cast<const uint2*>(hb + o1);
            uint2 u2 = *reinterpret_cast<const uint2*>(hb + o2);
            uint2 u3 = *reinterpret_cast<const uint2*>(hb + o3);
            fma8q(u0, q0, acc2);
            fma8q(u1, q1, acc2);
            fma8q(u2, q2, acc2);
            fma8q(u3, q3, acc2);
        }
    }

    float4 dsum = den4;
#pragma unroll
    for (int off = 1; off < 32; off <<= 1) {
        dsum.x += __shfl_xor(dsum.x, off);
        dsum.y += __shfl_xor(dsum.y, off);
        dsum.z += __shfl_xor(dsum.z, off);
        dsum.w += __shfl_xor(dsum.w, off);
    }
    const float inv = 1.0f / pick4(dsum, head);
    float4 bv0 = *reinterpret_cast<const float4*>(bias + c0);
    float4 bv1 = *reinterpret_cast<const float4*>(bias + c0 + 4);
    float v[8];
    v[0] = acc2[0][0] * inv + bv0.x; v[1] = acc2[0][1] * inv + bv0.y;
    v[2] = acc2[1][0] * inv + bv0.z; v[3] = acc2[1][1] * inv + bv0.w;
    v[4] = acc2[2][0] * inv + bv1.x; v[5] = acc2[2][1] * inv + bv1.y;
    v[6] = acc2[3][0] * inv + bv1.z; v[7] = acc2[3][1] * inv + bv1.w;

    float sum = 0.f;
#pragma unroll
    for (int c = 0; c < 8; ++c) sum += v[c];
#pragma unroll
    for (int off = 1; off < 32; off <<= 1) sum += __shfl_xor(sum, off);
    float mu = sum * (1.0f / 256.0f);
    float d[8], vs = 0.f;
#pragma unroll
    for (int c = 0; c < 8; ++c) { d[c] = v[c] - mu; vs = fmaf(d[c], d[c], vs); }
#pragma unroll
    for (int off = 1; off < 32; off <<= 1) vs += __shfl_xor(vs, off);
    float rstd = rsqrtf(vs * (1.0f / 256.0f) + LN_EPS);
    float4 gv0 = *reinterpret_cast<const float4*>(lng + c0);
    float4 gv1 = *reinterpret_cast<const float4*>(lng + c0 + 4);
    float4 bb0 = *reinterpret_cast<const float4*>(lnb + c0);
    float4 bb1 = *reinterpret_cast<const float4*>(lnb + c0 + 4);
    float g[8] = {gv0.x, gv0.y, gv0.z, gv0.w, gv1.x, gv1.y, gv1.z, gv1.w};
    float bbv[8] = {bb0.x, bb0.y, bb0.z, bb0.w, bb1.x, bb1.y, bb1.z, bb1.w};
    float o[8];
#pragma unroll
    for (int c = 0; c < 8; ++c) {
        float val = fmaf(d[c] * rstd, g[c], bbv[c]);
        o[c] = (val > 0.f) ? val : (__expf(val) - 1.0f);
    }

    if (FUSE_W2) {
        float4 wv0 = *reinterpret_cast<const float4*>(W2 + c0);
        float4 wv1 = *reinterpret_cast<const float4*>(W2 + c0 + 4);
        float wv[8] = {wv0.x, wv0.y, wv0.z, wv0.w, wv1.x, wv1.y, wv1.z, wv1.w};
        float p = 0.f;
#pragma unroll
        for (int c = 0; c < 8; ++c) p = fmaf(o[c], wv[c], p);
#pragma unroll
        for (int off = 1; off < 32; off <<= 1) p += __shfl_xor(p, off);
        if (lh == 0) h2[n] = p;
    } else {
        ushort yo[8];
#pragma unroll
        for (int c = 0; c < 8; ++c) yo[c] = f2bf(o[c]);
        *reinterpret_cast<uint4*>(Y + (size_t)n * 256 + c0) =
            *reinterpret_cast<const uint4*>(yo);
    }
}

// ---------------- layer 2 aggregation (H=1,C=1): 4 nodes/wave ----------------

__global__ __launch_bounds__(256) void k_agg2(
    const int* __restrict__ offs, const int* __restrict__ csr,
    const float* __restrict__ h2,
    const float* __restrict__ as2, const float* __restrict__ ad2,
    const float* __restrict__ b2, float* __restrict__ out, int N)
{
    const int tid = threadIdx.x;
    const int wid = tid >> 6;
    const int lane = tid & 63;
    const int quarter = lane >> 4;
    const int lq = lane & 15;
    const int n = blockIdx.x * 16 + wid * 4 + quarter;
    if (n >= N) return;
    const float asv = as2[0], adv = ad2[0];
    const float tval = adv * h2[n];
    const int beg = offs[n], end = offs[n + 1];

    float m = -1e30f, den = 0.f, num = 0.f;
    for (int i = beg + lq; i < end; i += 16) {
        float hv = h2[csr[i]];
        float e = fmaf(asv, hv, tval);
        e = fmaxf(e, NEG_SLOPE * e);
        float nm = fmaxf(m, e);
        float sc = __expf(m - nm);
        float p = __expf(e - nm);
        den = den * sc + p;
        num = fmaf(num, sc, p * hv);
        m = nm;
    }
#pragma unroll
    for (int o = 1; o < 16; o <<= 1) {
        float m2 = __shfl_xor(m, o);
        float d2 = __shfl_xor(den, o);
        float n2 = __shfl_xor(num, o);
        float nm = fmaxf(m, m2);
        float sA = __expf(m - nm);
        float sB = __expf(m2 - nm);
        den = den * sA + d2 * sB;
        num = num * sA + n2 * sB;
        m = nm;
    }
    if (lq == 0) out[n] = num / den + b2[0];
}

// ---------------- launch ----------------

extern "C" void kernel_launch(void* const* d_in, const int* in_sizes, int n_in,
                              void* d_out, int out_size, void* d_ws, size_t ws_size,
                              hipStream_t stream) {
    const float* x   = (const float*)d_in[0];
    const int*   ei  = (const int*)d_in[1];
    const float* W0  = (const float*)d_in[2];
    const float* as0 = (const float*)d_in[3];
    const float* ad0 = (const float*)d_in[4];
    const float* b0  = (const float*)d_in[5];
    const float* W1  = (const float*)d_in[6];
    const float* as1 = (const float*)d_in[7];
    const float* ad1 = (const float*)d_in[8];
    const float* b1  = (const float*)d_in[9];
    const float* W2  = (const float*)d_in[10];
    const float* as2 = (const float*)d_in[11];
    const float* ad2 = (const float*)d_in[12];
    const float* b2  = (const float*)d_in[13];
    const float* lng = (const float*)d_in[14];
    const float* lnb = (const float*)d_in[15];

    const int N = in_sizes[0] / 64;
    const int E = in_sizes[1] / 2;
    const int TOT = E + N;
    const int NBW = (N + 255) / 256;     // 256-node windows (<= 256)

    char* w = (char*)d_ws;
    auto alloc = [&](size_t bytes) -> void* {
        void* p = (void*)w;
        w += (bytes + 255) & ~(size_t)255;
        return p;
    };
    int*    offs   = (int*)alloc(sizeof(int) * (N + 1));
    int*    csr    = (int*)alloc(sizeof(int) * TOT);
    int*    wcnt   = (int*)alloc(sizeof(int) * 256);
    int*    wbase  = (int*)alloc(sizeof(int) * 256);
    int*    wcur   = (int*)alloc(sizeof(int) * 256 * 16);   // 64B-strided cursors
    unsigned long long* tmp = (unsigned long long*)alloc(sizeof(unsigned long long) * TOT);
    float*  sbuf   = (float*)alloc(sizeof(float) * N * 4);
    float*  tbuf   = (float*)alloc(sizeof(float) * N * 4);
    ushort* Xb     = (ushort*)alloc(sizeof(ushort) * (size_t)N * 64);
    ushort* Wt0    = (ushort*)alloc(sizeof(ushort) * 256 * 64);
    ushort* Wt1    = (ushort*)alloc(sizeof(ushort) * 256 * 256);
    uchar*  hq     = (uchar*)alloc(sizeof(uchar) * (size_t)N * 256);
    ushort* Yb     = (ushort*)alloc(sizeof(ushort) * (size_t)N * 256);
    float*  h2     = (float*)alloc(sizeof(float) * N);
    float*  out    = (float*)d_out;

    hipMemsetAsync(wcnt, 0, sizeof(int) * 256, stream);

    // fused pre-pass: dtype conversions + window counts
    const int pre_tot = N * 8 + 64 * 256 + 256 * 256 + TOT;
    k_pre<<<(pre_tot + 255) / 256, 256, 0, stream>>>(x, W0, W1, ei, Xb, Wt0, Wt1,
                                                     wcnt, N, E);

    // CSR build: scan -> binned scatter -> window-local CSR
    k_winscan<<<1, 256, 0, stream>>>(wcnt, wbase, wcur, NBW);
    k_binA<<<(TOT + 1023) / 1024, 1024, 0, stream>>>(ei, E, N, NBW, wcur, tmp);
    k_win<<<NBW, 256, 0, stream>>>(tmp, wbase, wcnt, NBW, N, offs, csr);

    // GEMM grid: 8 xcds x cpx chunks x 4 slices; each block does rbpc row-blocks
    const int nrb = (N + 63) / 64;
    const int cpx = 25;
    const int chunks = 8 * cpx;
    const int rbpc = (nrb + chunks - 1) / chunks;
    const int gemm_grid = chunks * 4;
    const int node_grid8 = (N + 7) / 8;
    const int node_grid16 = (N + 15) / 16;

    // layer 0
    k_gemm_mfma<64><<<gemm_grid, 256, 0, stream>>>(Xb, Wt0, as0, ad0, hq, sbuf, tbuf,
                                                   N, nrb, cpx, rbpc);
    k_agg_ln_elu<false><<<node_grid8, 256, 0, stream>>>(offs, csr, sbuf, tbuf, hq,
                                                        b0, lng, lnb, Yb, nullptr, nullptr, N);
    // layer 1 (+ fused 256->1 projection)
    k_gemm_mfma<256><<<gemm_grid, 256, 0, stream>>>(Yb, Wt1, as1, ad1, hq, sbuf, tbuf,
                                                    N, nrb, cpx, rbpc);
    k_agg_ln_elu<true><<<node_grid8, 256, 0, stream>>>(offs, csr, sbuf, tbuf, hq,
                                                       b1, lng, lnb, nullptr, W2, h2, N);
    // layer 2
    k_agg2<<<node_grid16, 256, 0, stream>>>(offs, csr, h2, as2, ad2, b2, out, N);
}

// Round 14
// 235.106 us; speedup vs baseline: 1.0688x; 1.0688x over previous
//
#include <hip/hip_runtime.h>
#include <math.h>

constexpr float NEG_SLOPE = 0.2f;
constexpr float LN_EPS = 1e-5f;

typedef __attribute__((ext_vector_type(8))) short short8;   // bf16x8 MFMA frag
typedef __attribute__((ext_vector_type(4))) float f32x4;    // MFMA acc
typedef __attribute__((ext_vector_type(2))) float f32x2;

__device__ inline ushort f2bf(float f) {        // fp32 -> bf16 RTN-even
    uint u = __float_as_uint(f);
    u += 0x7fffu + ((u >> 16) & 1u);
    return (ushort)(u >> 16);
}

__device__ inline float pick4(float4 v, int h) {
    float r = v.x;
    r = (h == 1) ? v.y : r;
    r = (h == 2) ? v.z : r;
    r = (h == 3) ? v.w : r;
    return r;
}

// fp8 e4m3 (OCP) encode/decode via gfx950 HW converters
__device__ inline uchar f2q(float v) {
    int r = __builtin_amdgcn_cvt_pk_fp8_f32(v, v, 0, false);
    return (uchar)(r & 0xff);
}

// packed: 4x v_pk_fma_f32 + 4x cvt_pk per edge (8 channels)
__device__ inline void fma8q(const uint2& u, float q, f32x2 acc[4]) {
    f32x2 qq = {q, q};
    acc[0] += qq * __builtin_amdgcn_cvt_pk_f32_fp8(u.x, false);
    acc[1] += qq * __builtin_amdgcn_cvt_pk_f32_fp8(u.x, true);
    acc[2] += qq * __builtin_amdgcn_cvt_pk_f32_fp8(u.y, false);
    acc[3] += qq * __builtin_amdgcn_cvt_pk_f32_fp8(u.y, true);
}

// ---------------- fused pre-pass: dtype conversions + window counts --------
// wcnt is 64B-strided (wcnt[w*16]) so block-flush atomics hit one cache line
// per window, not 16 windows/line (round-13 lesson: dense counter arrays
// serialize; padded ones don't).

__global__ __launch_bounds__(256) void k_pre(
    const float* __restrict__ x,
    const float* __restrict__ W0,
    const float* __restrict__ W1,
    const int* __restrict__ ei,
    ushort* __restrict__ Xb,
    ushort* __restrict__ Wt0,
    ushort* __restrict__ Wt1,
    int* __restrict__ wcnt, int N, int E) {
    __shared__ int lcnt[256];
    lcnt[threadIdx.x] = 0;
    __syncthreads();

    int i = blockIdx.x * blockDim.x + threadIdx.x;
    const int nx = N * 8;
    if (i < nx) {
        float4 a = *reinterpret_cast<const float4*>(x + (size_t)i * 8);
        float4 b = *reinterpret_cast<const float4*>(x + (size_t)i * 8 + 4);
        ushort u[8] = {f2bf(a.x), f2bf(a.y), f2bf(a.z), f2bf(a.w),
                       f2bf(b.x), f2bf(b.y), f2bf(b.z), f2bf(b.w)};
        *reinterpret_cast<uint4*>(Xb + (size_t)i * 8) = *reinterpret_cast<const uint4*>(u);
    } else {
        int j = i - nx;
        if (j < 64 * 256) {
            int k = j >> 8, c = j & 255;
            Wt0[(size_t)c * 64 + k] = f2bf(W0[j]);
        } else {
            j -= 64 * 256;
            if (j < 256 * 256) {
                int k = j >> 8, c = j & 255;
                Wt1[(size_t)c * 256 + k] = f2bf(W1[j]);
            } else {
                j -= 256 * 256;
                if (j < E + N) {
                    int dst = (j < E) ? ei[E + j] : (j - E);
                    atomicAdd(&lcnt[dst >> 8], 1);
                }
            }
        }
    }
    __syncthreads();
    int c = lcnt[threadIdx.x];
    if (c) atomicAdd(&wcnt[threadIdx.x * 16], c);   // padded: 1 window / line
}

// ---------------- CSR build: window-local, no global per-node atomics -------

// exclusive scan of window counts (nbw <= 256); wcur gets 64B-strided copy
__global__ __launch_bounds__(256) void k_winscan(const int* __restrict__ wcnt,
                                                 int* __restrict__ wbase,
                                                 int* __restrict__ wcur, int nbw) {
    __shared__ int buf[256];
    const int t = threadIdx.x;
    int v = (t < nbw) ? wcnt[t * 16] : 0;
    buf[t] = v;
    __syncthreads();
    for (int off = 1; off < 256; off <<= 1) {
        int a = (t >= off) ? buf[t - off] : 0;
        __syncthreads();
        buf[t] += a;
        __syncthreads();
    }
    int excl = buf[t] - v;
    if (t < nbw) { wbase[t] = excl; wcur[t * 16] = excl; }
}

// bin edges into per-window contiguous tmp regions (block-agg reservation)
__global__ __launch_bounds__(1024) void k_binA(const int* __restrict__ ei, int E, int N,
                                               int nbw, int* __restrict__ wcur,
                                               unsigned long long* __restrict__ tmp) {
    __shared__ int lcnt[256];
    __shared__ int lbase[256];
    const int tid = threadIdx.x;
    if (tid < 256) lcnt[tid] = 0;
    __syncthreads();
    int i = blockIdx.x * 1024 + tid;
    int src = 0, dst = 0, rank = 0, buc = 0;
    const bool valid = i < E + N;
    if (valid) {
        if (i < E) { src = ei[i]; dst = ei[E + i]; }
        else       { src = i - E; dst = i - E; }
        buc = dst >> 8;
        rank = atomicAdd(&lcnt[buc], 1);          // LDS atomic
    }
    __syncthreads();
    if (tid < 256) {
        int c = lcnt[tid];
        lbase[tid] = c ? atomicAdd(&wcur[tid * 16], c) : 0;
    }
    __syncthreads();
    if (valid)
        tmp[lbase[buc] + rank] = ((unsigned long long)(uint)dst << 32) | (uint)src;
}

// per-window: LDS histogram + scan -> offs; LDS-atomic scatter -> csr
__global__ __launch_bounds__(256) void k_win(const unsigned long long* __restrict__ tmp,
                                             const int* __restrict__ wbase,
                                             const int* __restrict__ wcnt,
                                             int nbw, int N,
                                             int* __restrict__ offs,
                                             int* __restrict__ csr) {
    __shared__ int hist[256];
    __shared__ int cur[256];
    __shared__ int buf[256];
    const int w = blockIdx.x;
    const int t = threadIdx.x;
    const int base = wbase[w];
    const int count = wcnt[w * 16];

    hist[t] = 0;
    __syncthreads();
    for (int i = t; i < count; i += 256) {
        int dst = (int)(tmp[base + i] >> 32);
        atomicAdd(&hist[dst & 255], 1);
    }
    __syncthreads();
    int v = hist[t];
    buf[t] = v;
    __syncthreads();
    for (int off = 1; off < 256; off <<= 1) {
        int a = (t >= off) ? buf[t - off] : 0;
        __syncthreads();
        buf[t] += a;
        __syncthreads();
    }
    int excl = buf[t] - v;
    cur[t] = excl;
    int node = w * 256 + t;
    if (node < N) offs[node] = base + excl;
    if (t == 0 && w == nbw - 1) offs[N] = base + count;
    __syncthreads();
    for (int i = t; i < count; i += 256) {
        unsigned long long e = tmp[base + i];
        int dst = (int)(e >> 32);
        int src = (int)(e & 0xffffffffu);
        int pos = base + atomicAdd(&cur[dst & 255], 1);
        csr[pos] = src;
    }
}

// ---------------- MFMA GEMM: h = Xb * W  (+ fused s,t scores) ----------------
// Xb: [N][K] bf16, Wt: [256][K] bf16, h: [N][256] fp8-e4m3, s,t: [N][4] fp32.

template <int K>
__global__ __launch_bounds__(256, 2) void k_gemm_mfma(
    const ushort* __restrict__ Xb, const ushort* __restrict__ Wt,
    const float* __restrict__ a_s, const float* __restrict__ a_d,
    uchar* __restrict__ h, float* __restrict__ s, float* __restrict__ t,
    int N, int nrb, int cpx, int rbpc)
{
    constexpr int KC = K / 32;
    __shared__ uchar hstage[4][16][72];    // fp8, padded row stride 72B

    const int tid = threadIdx.x;
    const int w = tid >> 6;
    const int l = tid & 63;
    const int lr = l & 15;
    const int lk = l >> 4;

    const int bid = blockIdx.x;
    const int xcd = bid & 7;
    const int j = bid >> 3;
    const int slice = j & 3;
    const int chunk = xcd * cpx + (j >> 2);
    const int rb0 = chunk * rbpc;
    const int rb1 = min(rb0 + rbpc, nrb);

    short8 b[4][KC];
#pragma unroll
    for (int ct = 0; ct < 4; ++ct) {
        const ushort* wp = Wt + (size_t)(slice * 64 + ct * 16 + lr) * K + lk * 8;
#pragma unroll
        for (int kc = 0; kc < KC; ++kc)
            b[ct][kc] = *reinterpret_cast<const short8*>(wp + kc * 32);
    }

    float asv[4], adv[4];
#pragma unroll
    for (int ct = 0; ct < 4; ++ct) {
        asv[ct] = a_s[slice * 64 + ct * 16 + lr];
        adv[ct] = a_d[slice * 64 + ct * 16 + lr];
    }

    for (int rb = rb0; rb < rb1; ++rb) {
        const int row0 = rb * 64 + w * 16;

        int arow = row0 + lr;
        arow = (arow < N) ? arow : (N - 1);
        const ushort* xp = Xb + (size_t)arow * K + lk * 8;
        short8 a[KC];
#pragma unroll
        for (int kc = 0; kc < KC; ++kc)
            a[kc] = *reinterpret_cast<const short8*>(xp + kc * 32);

        f32x4 acc[4];
#pragma unroll
        for (int ct = 0; ct < 4; ++ct) acc[ct] = (f32x4){0.f, 0.f, 0.f, 0.f};
#pragma unroll
        for (int ct = 0; ct < 4; ++ct)
#pragma unroll
            for (int kc = 0; kc < KC; ++kc)
                acc[ct] = __builtin_amdgcn_mfma_f32_16x16x32_bf16(a[kc], b[ct][kc], acc[ct], 0, 0, 0);

        // fused s,t scores (fp32)
        float ps[4] = {0.f, 0.f, 0.f, 0.f}, pt[4] = {0.f, 0.f, 0.f, 0.f};
#pragma unroll
        for (int jj = 0; jj < 4; ++jj) {
#pragma unroll
            for (int ct = 0; ct < 4; ++ct) {
                float v = acc[ct][jj];
                ps[jj] = fmaf(v, asv[ct], ps[jj]);
                pt[jj] = fmaf(v, adv[ct], pt[jj]);
            }
        }
#pragma unroll
        for (int jj = 0; jj < 4; ++jj) {
#pragma unroll
            for (int o = 1; o < 16; o <<= 1) {
                ps[jj] += __shfl_xor(ps[jj], o);
                pt[jj] += __shfl_xor(pt[jj], o);
            }
        }
        if (lr == 0) {
#pragma unroll
            for (int jj = 0; jj < 4; ++jj) {
                int row = row0 + lk * 4 + jj;
                if (row < N) {
                    s[(size_t)row * 4 + slice] = ps[jj];
                    t[(size_t)row * 4 + slice] = pt[jj];
                }
            }
        }

        // stage fp8 tile in LDS (per-wave private), store 64B row-chunks
#pragma unroll
        for (int ct = 0; ct < 4; ++ct)
#pragma unroll
            for (int jj = 0; jj < 4; ++jj)
                hstage[w][lk * 4 + jj][ct * 16 + lr] = f2q(acc[ct][jj]);
#pragma unroll
        for (int hf = 0; hf < 2; ++hf) {
            int r = (l >> 3) + hf * 8;      // 0..15
            int ch = l & 7;                 // 8B chunk within 64 cols
            int grow = rb * 64 + w * 16 + r;
            uint2 v = *reinterpret_cast<const uint2*>(&hstage[w][r][ch * 8]);
            if (grow < N)
                *reinterpret_cast<uint2*>(h + (size_t)grow * 256 + slice * 64 + ch * 8) = v;
        }
    }
}

// ---------------- aggregation (+ bias + LayerNorm + ELU) ----------------
// TWO nodes per wave: 32 lanes per node, lane owns 8 channels (8B fp8).
// Online softmax per 32-edge chunk; packed f32x2 accumulation (v_pk_fma_f32).

template <bool FUSE_W2>
__global__ __launch_bounds__(256) void k_agg_ln_elu(
    const int* __restrict__ offs, const int* __restrict__ csr,
    const float* __restrict__ s, const float* __restrict__ t,
    const uchar* __restrict__ h, const float* __restrict__ bias,
    const float* __restrict__ lng, const float* __restrict__ lnb,
    ushort* __restrict__ Y, const float* __restrict__ W2,
    float* __restrict__ h2, int N)
{
    __shared__ float p_s[4][2][32][4];
    __shared__ int off_s[4][2][32];

    const int tid = threadIdx.x;
    const int wid = tid >> 6;
    const int lane = tid & 63;
    const int half = lane >> 5;
    const int lh = lane & 31;
    const int n = blockIdx.x * 8 + wid * 2 + half;
    if (n >= N) return;
    const int head = lh >> 3;
    const int c0 = lh * 8;

    const float4 t4 = *reinterpret_cast<const float4*>(t + (size_t)n * 4);
    const int beg = offs[n], end = offs[n + 1];

    float4 m4 = make_float4(-1e30f, -1e30f, -1e30f, -1e30f);
    float4 den4 = make_float4(0.f, 0.f, 0.f, 0.f);
    f32x2 acc2[4];
#pragma unroll
    for (int c = 0; c < 4; ++c) acc2[c] = (f32x2){0.f, 0.f};

    const uchar* hb = h + lh * 8;
    float* pp = &p_s[wid][half][0][0];
    int* op = &off_s[wid][half][0];

    for (int base = beg; base < end; base += 32) {
        const int cnt = min(32, end - base);
        int src = 0;
        float4 e4 = make_float4(-1e30f, -1e30f, -1e30f, -1e30f);
        if (lh < cnt) {
            src = csr[base + lh];
            float4 sv = *reinterpret_cast<const float4*>(s + (size_t)src * 4);
            float ex = sv.x + t4.x, ey = sv.y + t4.y, ez = sv.z + t4.z, ew = sv.w + t4.w;
            e4.x = fmaxf(ex, NEG_SLOPE * ex);
            e4.y = fmaxf(ey, NEG_SLOPE * ey);
            e4.z = fmaxf(ez, NEG_SLOPE * ez);
            e4.w = fmaxf(ew, NEG_SLOPE * ew);
        }
        float4 bm = e4;
#pragma unroll
        for (int off = 1; off < 32; off <<= 1) {
            bm.x = fmaxf(bm.x, __shfl_xor(bm.x, off));
            bm.y = fmaxf(bm.y, __shfl_xor(bm.y, off));
            bm.z = fmaxf(bm.z, __shfl_xor(bm.z, off));
            bm.w = fmaxf(bm.w, __shfl_xor(bm.w, off));
        }
        float4 newm = make_float4(fmaxf(m4.x, bm.x), fmaxf(m4.y, bm.y),
                                  fmaxf(m4.z, bm.z), fmaxf(m4.w, bm.w));
        float4 sc4 = make_float4(__expf(m4.x - newm.x), __expf(m4.y - newm.y),
                                 __expf(m4.z - newm.z), __expf(m4.w - newm.w));
        m4 = newm;
        float sch = pick4(sc4, head);
        f32x2 sch2 = {sch, sch};
#pragma unroll
        for (int c = 0; c < 4; ++c) acc2[c] *= sch2;
        float4 p4 = make_float4(__expf(e4.x - newm.x), __expf(e4.y - newm.y),
                                __expf(e4.z - newm.z), __expf(e4.w - newm.w));
        den4.x = den4.x * sc4.x + p4.x;
        den4.y = den4.y * sc4.y + p4.y;
        den4.z = den4.z * sc4.z + p4.z;
        den4.w = den4.w * sc4.w + p4.w;

        *reinterpret_cast<float4*>(&p_s[wid][half][lh][0]) = p4;
        op[lh] = src << 8;              // byte offset of fp8 h row
        asm volatile("s_waitcnt lgkmcnt(0)" ::: "memory");

        // padded gather, 4 edges per iteration (pad entries have p == 0)
        for (int j0 = 0; j0 < cnt; j0 += 4) {
            int o0 = op[j0 + 0];
            int o1 = op[j0 + 1];
            int o2 = op[j0 + 2];
            int o3 = op[j0 + 3];
            float q0 = pp[(j0 + 0) * 4 + head];
            float q1 = pp[(j0 + 1) * 4 + head];
            float q2 = pp[(j0 + 2) * 4 + head];
            float q3 = pp[(j0 + 3) * 4 + head];
            uint2 u0 = *reinterpret_cast<const uint2*>(hb + o0);
            uint2 u1 = *reinterpret_cast<const uint2*>(hb + o1);
            uint2 u2 = *reinterpret_cast<const uint2*>(hb + o2);
            uint2 u3 = *reinterpret_cast<const uint2*>(hb + o3);
            fma8q(u0, q0, acc2);
            fma8q(u1, q1, acc2);
            fma8q(u2, q2, acc2);
            fma8q(u3, q3, acc2);
        }
    }

    float4 dsum = den4;
#pragma unroll
    for (int off = 1; off < 32; off <<= 1) {
        dsum.x += __shfl_xor(dsum.x, off);
        dsum.y += __shfl_xor(dsum.y, off);
        dsum.z += __shfl_xor(dsum.z, off);
        dsum.w += __shfl_xor(dsum.w, off);
    }
    const float inv = 1.0f / pick4(dsum, head);
    float4 bv0 = *reinterpret_cast<const float4*>(bias + c0);
    float4 bv1 = *reinterpret_cast<const float4*>(bias + c0 + 4);
    float v[8];
    v[0] = acc2[0][0] * inv + bv0.x; v[1] = acc2[0][1] * inv + bv0.y;
    v[2] = acc2[1][0] * inv + bv0.z; v[3] = acc2[1][1] * inv + bv0.w;
    v[4] = acc2[2][0] * inv + bv1.x; v[5] = acc2[2][1] * inv + bv1.y;
    v[6] = acc2[3][0] * inv + bv1.z; v[7] = acc2[3][1] * inv + bv1.w;

    float sum = 0.f;
#pragma unroll
    for (int c = 0; c < 8; ++c) sum += v[c];
#pragma unroll
    for (int off = 1; off < 32; off <<= 1) sum += __shfl_xor(sum, off);
    float mu = sum * (1.0f / 256.0f);
    float d[8], vs = 0.f;
#pragma unroll
    for (int c = 0; c < 8; ++c) { d[c] = v[c] - mu; vs = fmaf(d[c], d[c], vs); }
#pragma unroll
    for (int off = 1; off < 32; off <<= 1) vs += __shfl_xor(vs, off);
    float rstd = rsqrtf(vs * (1.0f / 256.0f) + LN_EPS);
    float4 gv0 = *reinterpret_cast<const float4*>(lng + c0);
    float4 gv1 = *reinterpret_cast<const float4*>(lng + c0 + 4);
    float4 bb0 = *reinterpret_cast<const float4*>(lnb + c0);
    float4 bb1 = *reinterpret_cast<const float4*>(lnb + c0 + 4);
    float g[8] = {gv0.x, gv0.y, gv0.z, gv0.w, gv1.x, gv1.y, gv1.z, gv1.w};
    float bbv[8] = {bb0.x, bb0.y, bb0.z, bb0.w, bb1.x, bb1.y, bb1.z, bb1.w};
    float o[8];
#pragma unroll
    for (int c = 0; c < 8; ++c) {
        float val = fmaf(d[c] * rstd, g[c], bbv[c]);
        o[c] = (val > 0.f) ? val : (__expf(val) - 1.0f);
    }

    if (FUSE_W2) {
        float4 wv0 = *reinterpret_cast<const float4*>(W2 + c0);
        float4 wv1 = *reinterpret_cast<const float4*>(W2 + c0 + 4);
        float wv[8] = {wv0.x, wv0.y, wv0.z, wv0.w, wv1.x, wv1.y, wv1.z, wv1.w};
        float p = 0.f;
#pragma unroll
        for (int c = 0; c < 8; ++c) p = fmaf(o[c], wv[c], p);
#pragma unroll
        for (int off = 1; off < 32; off <<= 1) p += __shfl_xor(p, off);
        if (lh == 0) h2[n] = p;
    } else {
        ushort yo[8];
#pragma unroll
        for (int c = 0; c < 8; ++c) yo[c] = f2bf(o[c]);
        *reinterpret_cast<uint4*>(Y + (size_t)n * 256 + c0) =
            *reinterpret_cast<const uint4*>(yo);
    }
}

// ---------------- layer 2 aggregation (H=1,C=1): 4 nodes/wave ----------------

__global__ __launch_bounds__(256) void k_agg2(
    const int* __restrict__ offs, const int* __restrict__ csr,
    const float* __restrict__ h2,
    const float* __restrict__ as2, const float* __restrict__ ad2,
    const float* __restrict__ b2, float* __restrict__ out, int N)
{
    const int tid = threadIdx.x;
    const int wid = tid >> 6;
    const int lane = tid & 63;
    const int quarter = lane >> 4;
    const int lq = lane & 15;
    const int n = blockIdx.x * 16 + wid * 4 + quarter;
    if (n >= N) return;
    const float asv = as2[0], adv = ad2[0];
    const float tval = adv * h2[n];
    const int beg = offs[n], end = offs[n + 1];

    float m = -1e30f, den = 0.f, num = 0.f;
    for (int i = beg + lq; i < end; i += 16) {
        float hv = h2[csr[i]];
        float e = fmaf(asv, hv, tval);
        e = fmaxf(e, NEG_SLOPE * e);
        float nm = fmaxf(m, e);
        float sc = __expf(m - nm);
        float p = __expf(e - nm);
        den = den * sc + p;
        num = fmaf(num, sc, p * hv);
        m = nm;
    }
#pragma unroll
    for (int o = 1; o < 16; o <<= 1) {
        float m2 = __shfl_xor(m, o);
        float d2 = __shfl_xor(den, o);
        float n2 = __shfl_xor(num, o);
        float nm = fmaxf(m, m2);
        float sA = __expf(m - nm);
        float sB = __expf(m2 - nm);
        den = den * sA + d2 * sB;
        num = num * sA + n2 * sB;
        m = nm;
    }
    if (lq == 0) out[n] = num / den + b2[0];
}

// ---------------- launch ----------------

extern "C" void kernel_launch(void* const* d_in, const int* in_sizes, int n_in,
                              void* d_out, int out_size, void* d_ws, size_t ws_size,
                              hipStream_t stream) {
    const float* x   = (const float*)d_in[0];
    const int*   ei  = (const int*)d_in[1];
    const float* W0  = (const float*)d_in[2];
    const float* as0 = (const float*)d_in[3];
    const float* ad0 = (const float*)d_in[4];
    const float* b0  = (const float*)d_in[5];
    const float* W1  = (const float*)d_in[6];
    const float* as1 = (const float*)d_in[7];
    const float* ad1 = (const float*)d_in[8];
    const float* b1  = (const float*)d_in[9];
    const float* W2  = (const float*)d_in[10];
    const float* as2 = (const float*)d_in[11];
    const float* ad2 = (const float*)d_in[12];
    const float* b2  = (const float*)d_in[13];
    const float* lng = (const float*)d_in[14];
    const float* lnb = (const float*)d_in[15];

    const int N = in_sizes[0] / 64;
    const int E = in_sizes[1] / 2;
    const int TOT = E + N;
    const int NBW = (N + 255) / 256;     // 256-node windows (<= 256)

    char* w = (char*)d_ws;
    auto alloc = [&](size_t bytes) -> void* {
        void* p = (void*)w;
        w += (bytes + 255) & ~(size_t)255;
        return p;
    };
    int*    offs   = (int*)alloc(sizeof(int) * (N + 1));
    int*    csr    = (int*)alloc(sizeof(int) * TOT);
    int*    wcnt   = (int*)alloc(sizeof(int) * 256 * 16);   // 64B-strided counts
    int*    wbase  = (int*)alloc(sizeof(int) * 256);
    int*    wcur   = (int*)alloc(sizeof(int) * 256 * 16);   // 64B-strided cursors
    unsigned long long* tmp = (unsigned long long*)alloc(sizeof(unsigned long long) * TOT);
    float*  sbuf   = (float*)alloc(sizeof(float) * N * 4);
    float*  tbuf   = (float*)alloc(sizeof(float) * N * 4);
    ushort* Xb     = (ushort*)alloc(sizeof(ushort) * (size_t)N * 64);
    ushort* Wt0    = (ushort*)alloc(sizeof(ushort) * 256 * 64);
    ushort* Wt1    = (ushort*)alloc(sizeof(ushort) * 256 * 256);
    uchar*  hq     = (uchar*)alloc(sizeof(uchar) * (size_t)N * 256);
    ushort* Yb     = (ushort*)alloc(sizeof(ushort) * (size_t)N * 256);
    float*  h2     = (float*)alloc(sizeof(float) * N);
    float*  out    = (float*)d_out;

    hipMemsetAsync(wcnt, 0, sizeof(int) * 256 * 16, stream);

    // fused pre-pass: dtype conversions + window counts (padded counters)
    const int pre_tot = N * 8 + 64 * 256 + 256 * 256 + TOT;
    k_pre<<<(pre_tot + 255) / 256, 256, 0, stream>>>(x, W0, W1, ei, Xb, Wt0, Wt1,
                                                     wcnt, N, E);

    // CSR build: scan -> binned scatter -> window-local CSR
    k_winscan<<<1, 256, 0, stream>>>(wcnt, wbase, wcur, NBW);
    k_binA<<<(TOT + 1023) / 1024, 1024, 0, stream>>>(ei, E, N, NBW, wcur, tmp);
    k_win<<<NBW, 256, 0, stream>>>(tmp, wbase, wcnt, NBW, N, offs, csr);

    // GEMM grid: 8 xcds x cpx chunks x 4 slices; each block does rbpc row-blocks
    const int nrb = (N + 63) / 64;
    const int cpx = 25;
    const int chunks = 8 * cpx;
    const int rbpc = (nrb + chunks - 1) / chunks;
    const int gemm_grid = chunks * 4;
    const int node_grid8 = (N + 7) / 8;
    const int node_grid16 = (N + 15) / 16;

    // layer 0
    k_gemm_mfma<64><<<gemm_grid, 256, 0, stream>>>(Xb, Wt0, as0, ad0, hq, sbuf, tbuf,
                                                   N, nrb, cpx, rbpc);
    k_agg_ln_elu<false><<<node_grid8, 256, 0, stream>>>(offs, csr, sbuf, tbuf, hq,
                                                        b0, lng, lnb, Yb, nullptr, nullptr, N);
    // layer 1 (+ fused 256->1 projection)
    k_gemm_mfma<256><<<gemm_grid, 256, 0, stream>>>(Yb, Wt1, as1, ad1, hq, sbuf, tbuf,
                                                    N, nrb, cpx, rbpc);
    k_agg_ln_elu<true><<<node_grid8, 256, 0, stream>>>(offs, csr, sbuf, tbuf, hq,
                                                       b1, lng, lnb, nullptr, W2, h2, N);
    // layer 2
    k_agg2<<<node_grid16, 256, 0, stream>>>(offs, csr, h2, as2, ad2, b2, out, N);
}

// Round 15
// 184.695 us; speedup vs baseline: 1.3605x; 1.2729x over previous
//
#include <hip/hip_runtime.h>
#include <math.h>

constexpr float NEG_SLOPE = 0.2f;
constexpr float LN_EPS = 1e-5f;

typedef __attribute__((ext_vector_type(8))) short short8;   // bf16x8 MFMA frag
typedef __attribute__((ext_vector_type(4))) float f32x4;    // MFMA acc
typedef __attribute__((ext_vector_type(2))) float f32x2;

__device__ inline ushort f2bf(float f) {        // fp32 -> bf16 RTN-even
    uint u = __float_as_uint(f);
    u += 0x7fffu + ((u >> 16) & 1u);
    return (ushort)(u >> 16);
}

__device__ inline float pick4(float4 v, int h) {
    float r = v.x;
    r = (h == 1) ? v.y : r;
    r = (h == 2) ? v.z : r;
    r = (h == 3) ? v.w : r;
    return r;
}

// fp8 e4m3 (OCP) encode/decode via gfx950 HW converters
__device__ inline uchar f2q(float v) {
    int r = __builtin_amdgcn_cvt_pk_fp8_f32(v, v, 0, false);
    return (uchar)(r & 0xff);
}

// packed: 4x v_pk_fma_f32 + 4x cvt_pk per edge (8 channels)
__device__ inline void fma8q(const uint2& u, float q, f32x2 acc[4]) {
    f32x2 qq = {q, q};
    acc[0] += qq * __builtin_amdgcn_cvt_pk_f32_fp8(u.x, false);
    acc[1] += qq * __builtin_amdgcn_cvt_pk_f32_fp8(u.x, true);
    acc[2] += qq * __builtin_amdgcn_cvt_pk_f32_fp8(u.y, false);
    acc[3] += qq * __builtin_amdgcn_cvt_pk_f32_fp8(u.y, true);
}

// ---------------- pre-pass: dtype conversions only ----------------

__global__ void k_pre(const float* __restrict__ x,
                      const float* __restrict__ W0,
                      const float* __restrict__ W1,
                      ushort* __restrict__ Xb,
                      ushort* __restrict__ Wt0,
                      ushort* __restrict__ Wt1, int N) {
    int i = blockIdx.x * blockDim.x + threadIdx.x;
    const int nx = N * 8;
    if (i < nx) {
        float4 a = *reinterpret_cast<const float4*>(x + (size_t)i * 8);
        float4 b = *reinterpret_cast<const float4*>(x + (size_t)i * 8 + 4);
        ushort u[8] = {f2bf(a.x), f2bf(a.y), f2bf(a.z), f2bf(a.w),
                       f2bf(b.x), f2bf(b.y), f2bf(b.z), f2bf(b.w)};
        *reinterpret_cast<uint4*>(Xb + (size_t)i * 8) = *reinterpret_cast<const uint4*>(u);
        return;
    }
    i -= nx;
    if (i < 64 * 256) {
        int k = i >> 8, c = i & 255;
        Wt0[(size_t)c * 64 + k] = f2bf(W0[i]);
        return;
    }
    i -= 64 * 256;
    if (i < 256 * 256) {
        int k = i >> 8, c = i & 255;
        Wt1[(size_t)c * 256 + k] = f2bf(W1[i]);
    }
}

// ---------------- CSR build: ZERO global atomics ----------------
// k_cnt:   per-block LDS histogram -> bcnts[blk][256] (plain writes)
// k_scanA: per-window scan over blocks (in-place exclusive) + wtot
// k_scanB: scan wtot -> wbase
// k_binA:  rank via LDS atomic; base = wbase[w] + bcnts[blk][w]
// k_win:   per-window LDS hist/scan -> offs, csr

__global__ __launch_bounds__(1024) void k_cnt(const int* __restrict__ ei, int E, int N,
                                              int* __restrict__ bcnts) {
    __shared__ int lcnt[256];
    const int tid = threadIdx.x;
    if (tid < 256) lcnt[tid] = 0;
    __syncthreads();
    int i = blockIdx.x * 1024 + tid;
    if (i < E + N) {
        int dst = (i < E) ? ei[E + i] : (i - E);
        atomicAdd(&lcnt[dst >> 8], 1);
    }
    __syncthreads();
    if (tid < 256) bcnts[(size_t)blockIdx.x * 256 + tid] = lcnt[tid];
}

// one block per window: exclusive-scan bcnts[.][w] over nb blocks, in place
__global__ __launch_bounds__(256) void k_scanA(int* __restrict__ bcnts, int nb,
                                               int* __restrict__ wtot) {
    __shared__ int wsum[4];
    const int w = blockIdx.x;
    const int t = threadIdx.x;
    const int lane = t & 63;
    const int wv = t >> 6;
    int carry = 0;
    for (int base = 0; base < nb; base += 256) {
        int idx = base + t;
        int v = (idx < nb) ? bcnts[(size_t)idx * 256 + w] : 0;
        int sv = v;
#pragma unroll
        for (int off = 1; off < 64; off <<= 1) {
            int u = __shfl_up(sv, off);
            if (lane >= off) sv += u;
        }
        if (lane == 63) wsum[wv] = sv;
        __syncthreads();
        int add = 0;
#pragma unroll
        for (int k = 0; k < 4; ++k) add += (k < wv) ? wsum[k] : 0;
        int total = wsum[0] + wsum[1] + wsum[2] + wsum[3];
        if (idx < nb) bcnts[(size_t)idx * 256 + w] = carry + add + sv - v;  // exclusive
        carry += total;
        __syncthreads();
    }
    if (t == 0) wtot[w] = carry;
}

// exclusive scan of wtot (nbw <= 256) -> wbase
__global__ __launch_bounds__(256) void k_scanB(const int* __restrict__ wtot,
                                               int* __restrict__ wbase, int nbw) {
    __shared__ int buf[256];
    const int t = threadIdx.x;
    int v = (t < nbw) ? wtot[t] : 0;
    buf[t] = v;
    __syncthreads();
    for (int off = 1; off < 256; off <<= 1) {
        int a = (t >= off) ? buf[t - off] : 0;
        __syncthreads();
        buf[t] += a;
        __syncthreads();
    }
    if (t < nbw) wbase[t] = buf[t] - v;
}

// bin edges into per-window contiguous tmp regions; bases precomputed
__global__ __launch_bounds__(1024) void k_binA(const int* __restrict__ ei, int E, int N,
                                               const int* __restrict__ bcnts,
                                               const int* __restrict__ wbase,
                                               unsigned long long* __restrict__ tmp) {
    __shared__ int lcnt[256];
    __shared__ int lbase[256];
    const int tid = threadIdx.x;
    if (tid < 256) lcnt[tid] = 0;
    __syncthreads();
    int i = blockIdx.x * 1024 + tid;
    int src = 0, dst = 0, rank = 0, buc = 0;
    const bool valid = i < E + N;
    if (valid) {
        if (i < E) { src = ei[i]; dst = ei[E + i]; }
        else       { src = i - E; dst = i - E; }
        buc = dst >> 8;
        rank = atomicAdd(&lcnt[buc], 1);          // LDS atomic only
    }
    __syncthreads();
    if (tid < 256)
        lbase[tid] = wbase[tid] + bcnts[(size_t)blockIdx.x * 256 + tid];
    __syncthreads();
    if (valid)
        tmp[lbase[buc] + rank] = ((unsigned long long)(uint)dst << 32) | (uint)src;
}

// per-window: LDS histogram + scan -> offs; LDS-atomic scatter -> csr
__global__ __launch_bounds__(256) void k_win(const unsigned long long* __restrict__ tmp,
                                             const int* __restrict__ wbase,
                                             const int* __restrict__ wtot,
                                             int nbw, int N,
                                             int* __restrict__ offs,
                                             int* __restrict__ csr) {
    __shared__ int hist[256];
    __shared__ int cur[256];
    __shared__ int buf[256];
    const int w = blockIdx.x;
    const int t = threadIdx.x;
    const int base = wbase[w];
    const int count = wtot[w];

    hist[t] = 0;
    __syncthreads();
    for (int i = t; i < count; i += 256) {
        int dst = (int)(tmp[base + i] >> 32);
        atomicAdd(&hist[dst & 255], 1);
    }
    __syncthreads();
    int v = hist[t];
    buf[t] = v;
    __syncthreads();
    for (int off = 1; off < 256; off <<= 1) {
        int a = (t >= off) ? buf[t - off] : 0;
        __syncthreads();
        buf[t] += a;
        __syncthreads();
    }
    int excl = buf[t] - v;
    cur[t] = excl;
    int node = w * 256 + t;
    if (node < N) offs[node] = base + excl;
    if (t == 0 && w == nbw - 1) offs[N] = base + count;
    __syncthreads();
    for (int i = t; i < count; i += 256) {
        unsigned long long e = tmp[base + i];
        int dst = (int)(e >> 32);
        int src = (int)(e & 0xffffffffu);
        int pos = base + atomicAdd(&cur[dst & 255], 1);
        csr[pos] = src;
    }
}

// ---------------- MFMA GEMM: h = Xb * W  (+ fused s,t scores) ----------------
// Xb: [N][K] bf16, Wt: [256][K] bf16, h: [N][256] fp8-e4m3, s,t: [N][4] fp32.

template <int K>
__global__ __launch_bounds__(256, 2) void k_gemm_mfma(
    const ushort* __restrict__ Xb, const ushort* __restrict__ Wt,
    const float* __restrict__ a_s, const float* __restrict__ a_d,
    uchar* __restrict__ h, float* __restrict__ s, float* __restrict__ t,
    int N, int nrb, int cpx, int rbpc)
{
    constexpr int KC = K / 32;
    __shared__ uchar hstage[4][16][72];    // fp8, padded row stride 72B

    const int tid = threadIdx.x;
    const int w = tid >> 6;
    const int l = tid & 63;
    const int lr = l & 15;
    const int lk = l >> 4;

    const int bid = blockIdx.x;
    const int xcd = bid & 7;
    const int j = bid >> 3;
    const int slice = j & 3;
    const int chunk = xcd * cpx + (j >> 2);
    const int rb0 = chunk * rbpc;
    const int rb1 = min(rb0 + rbpc, nrb);

    short8 b[4][KC];
#pragma unroll
    for (int ct = 0; ct < 4; ++ct) {
        const ushort* wp = Wt + (size_t)(slice * 64 + ct * 16 + lr) * K + lk * 8;
#pragma unroll
        for (int kc = 0; kc < KC; ++kc)
            b[ct][kc] = *reinterpret_cast<const short8*>(wp + kc * 32);
    }

    float asv[4], adv[4];
#pragma unroll
    for (int ct = 0; ct < 4; ++ct) {
        asv[ct] = a_s[slice * 64 + ct * 16 + lr];
        adv[ct] = a_d[slice * 64 + ct * 16 + lr];
    }

    for (int rb = rb0; rb < rb1; ++rb) {
        const int row0 = rb * 64 + w * 16;

        int arow = row0 + lr;
        arow = (arow < N) ? arow : (N - 1);
        const ushort* xp = Xb + (size_t)arow * K + lk * 8;
        short8 a[KC];
#pragma unroll
        for (int kc = 0; kc < KC; ++kc)
            a[kc] = *reinterpret_cast<const short8*>(xp + kc * 32);

        f32x4 acc[4];
#pragma unroll
        for (int ct = 0; ct < 4; ++ct) acc[ct] = (f32x4){0.f, 0.f, 0.f, 0.f};
#pragma unroll
        for (int ct = 0; ct < 4; ++ct)
#pragma unroll
            for (int kc = 0; kc < KC; ++kc)
                acc[ct] = __builtin_amdgcn_mfma_f32_16x16x32_bf16(a[kc], b[ct][kc], acc[ct], 0, 0, 0);

        // fused s,t scores (fp32)
        float ps[4] = {0.f, 0.f, 0.f, 0.f}, pt[4] = {0.f, 0.f, 0.f, 0.f};
#pragma unroll
        for (int jj = 0; jj < 4; ++jj) {
#pragma unroll
            for (int ct = 0; ct < 4; ++ct) {
                float v = acc[ct][jj];
                ps[jj] = fmaf(v, asv[ct], ps[jj]);
                pt[jj] = fmaf(v, adv[ct], pt[jj]);
            }
        }
#pragma unroll
        for (int jj = 0; jj < 4; ++jj) {
#pragma unroll
            for (int o = 1; o < 16; o <<= 1) {
                ps[jj] += __shfl_xor(ps[jj], o);
                pt[jj] += __shfl_xor(pt[jj], o);
            }
        }
        if (lr == 0) {
#pragma unroll
            for (int jj = 0; jj < 4; ++jj) {
                int row = row0 + lk * 4 + jj;
                if (row < N) {
                    s[(size_t)row * 4 + slice] = ps[jj];
                    t[(size_t)row * 4 + slice] = pt[jj];
                }
            }
        }

        // stage fp8 tile in LDS (per-wave private), store 64B row-chunks
#pragma unroll
        for (int ct = 0; ct < 4; ++ct)
#pragma unroll
            for (int jj = 0; jj < 4; ++jj)
                hstage[w][lk * 4 + jj][ct * 16 + lr] = f2q(acc[ct][jj]);
#pragma unroll
        for (int hf = 0; hf < 2; ++hf) {
            int r = (l >> 3) + hf * 8;      // 0..15
            int ch = l & 7;                 // 8B chunk within 64 cols
            int grow = rb * 64 + w * 16 + r;
            uint2 v = *reinterpret_cast<const uint2*>(&hstage[w][r][ch * 8]);
            if (grow < N)
                *reinterpret_cast<uint2*>(h + (size_t)grow * 256 + slice * 64 + ch * 8) = v;
        }
    }
}

// ---------------- aggregation (+ bias + LayerNorm + ELU) ----------------
// TWO nodes per wave: 32 lanes per node, lane owns 8 channels (8B fp8).
// Online softmax per 32-edge chunk; packed f32x2 accumulation (v_pk_fma_f32).

template <bool FUSE_W2>
__global__ __launch_bounds__(256) void k_agg_ln_elu(
    const int* __restrict__ offs, const int* __restrict__ csr,
    const float* __restrict__ s, const float* __restrict__ t,
    const uchar* __restrict__ h, const float* __restrict__ bias,
    const float* __restrict__ lng, const float* __restrict__ lnb,
    ushort* __restrict__ Y, const float* __restrict__ W2,
    float* __restrict__ h2, int N)
{
    __shared__ float p_s[4][2][32][4];
    __shared__ int off_s[4][2][32];

    const int tid = threadIdx.x;
    const int wid = tid >> 6;
    const int lane = tid & 63;
    const int half = lane >> 5;
    const int lh = lane & 31;
    const int n = blockIdx.x * 8 + wid * 2 + half;
    if (n >= N) return;
    const int head = lh >> 3;
    const int c0 = lh * 8;

    const float4 t4 = *reinterpret_cast<const float4*>(t + (size_t)n * 4);
    const int beg = offs[n], end = offs[n + 1];

    float4 m4 = make_float4(-1e30f, -1e30f, -1e30f, -1e30f);
    float4 den4 = make_float4(0.f, 0.f, 0.f, 0.f);
    f32x2 acc2[4];
#pragma unroll
    for (int c = 0; c < 4; ++c) acc2[c] = (f32x2){0.f, 0.f};

    const uchar* hb = h + lh * 8;
    float* pp = &p_s[wid][half][0][0];
    int* op = &off_s[wid][half][0];

    for (int base = beg; base < end; base += 32) {
        const int cnt = min(32, end - base);
        int src = 0;
        float4 e4 = make_float4(-1e30f, -1e30f, -1e30f, -1e30f);
        if (lh < cnt) {
            src = csr[base + lh];
            float4 sv = *reinterpret_cast<const float4*>(s + (size_t)src * 4);
            float ex = sv.x + t4.x, ey = sv.y + t4.y, ez = sv.z + t4.z, ew = sv.w + t4.w;
            e4.x = fmaxf(ex, NEG_SLOPE * ex);
            e4.y = fmaxf(ey, NEG_SLOPE * ey);
            e4.z = fmaxf(ez, NEG_SLOPE * ez);
            e4.w = fmaxf(ew, NEG_SLOPE * ew);
        }
        float4 bm = e4;
#pragma unroll
        for (int off = 1; off < 32; off <<= 1) {
            bm.x = fmaxf(bm.x, __shfl_xor(bm.x, off));
            bm.y = fmaxf(bm.y, __shfl_xor(bm.y, off));
            bm.z = fmaxf(bm.z, __shfl_xor(bm.z, off));
            bm.w = fmaxf(bm.w, __shfl_xor(bm.w, off));
        }
        float4 newm = make_float4(fmaxf(m4.x, bm.x), fmaxf(m4.y, bm.y),
                                  fmaxf(m4.z, bm.z), fmaxf(m4.w, bm.w));
        float4 sc4 = make_float4(__expf(m4.x - newm.x), __expf(m4.y - newm.y),
                                 __expf(m4.z - newm.z), __expf(m4.w - newm.w));
        m4 = newm;
        float sch = pick4(sc4, head);
        f32x2 sch2 = {sch, sch};
#pragma unroll
        for (int c = 0; c < 4; ++c) acc2[c] *= sch2;
        float4 p4 = make_float4(__expf(e4.x - newm.x), __expf(e4.y - newm.y),
                                __expf(e4.z - newm.z), __expf(e4.w - newm.w));
        den4.x = den4.x * sc4.x + p4.x;
        den4.y = den4.y * sc4.y + p4.y;
        den4.z = den4.z * sc4.z + p4.z;
        den4.w = den4.w * sc4.w + p4.w;

        *reinterpret_cast<float4*>(&p_s[wid][half][lh][0]) = p4;
        op[lh] = src << 8;              // byte offset of fp8 h row
        asm volatile("s_waitcnt lgkmcnt(0)" ::: "memory");

        // padded gather, 4 edges per iteration (pad entries have p == 0)
        for (int j0 = 0; j0 < cnt; j0 += 4) {
            int o0 = op[j0 + 0];
            int o1 = op[j0 + 1];
            int o2 = op[j0 + 2];
            int o3 = op[j0 + 3];
            float q0 = pp[(j0 + 0) * 4 + head];
            float q1 = pp[(j0 + 1) * 4 + head];
            float q2 = pp[(j0 + 2) * 4 + head];
            float q3 = pp[(j0 + 3) * 4 + head];
            uint2 u0 = *reinterpret_cast<const uint2*>(hb + o0);
            uint2 u1 = *reinterpret_cast<const uint2*>(hb + o1);
            uint2 u2 = *reinterpret_cast<const uint2*>(hb + o2);
            uint2 u3 = *reinterpret_cast<const uint2*>(hb + o3);
            fma8q(u0, q0, acc2);
            fma8q(u1, q1, acc2);
            fma8q(u2, q2, acc2);
            fma8q(u3, q3, acc2);
        }
    }

    float4 dsum = den4;
#pragma unroll
    for (int off = 1; off < 32; off <<= 1) {
        dsum.x += __shfl_xor(dsum.x, off);
        dsum.y += __shfl_xor(dsum.y, off);
        dsum.z += __shfl_xor(dsum.z, off);
        dsum.w += __shfl_xor(dsum.w, off);
    }
    const float inv = 1.0f / pick4(dsum, head);
    float4 bv0 = *reinterpret_cast<const float4*>(bias + c0);
    float4 bv1 = *reinterpret_cast<const float4*>(bias + c0 + 4);
    float v[8];
    v[0] = acc2[0][0] * inv + bv0.x; v[1] = acc2[0][1] * inv + bv0.y;
    v[2] = acc2[1][0] * inv + bv0.z; v[3] = acc2[1][1] * inv + bv0.w;
    v[4] = acc2[2][0] * inv + bv1.x; v[5] = acc2[2][1] * inv + bv1.y;
    v[6] = acc2[3][0] * inv + bv1.z; v[7] = acc2[3][1] * inv + bv1.w;

    float sum = 0.f;
#pragma unroll
    for (int c = 0; c < 8; ++c) sum += v[c];
#pragma unroll
    for (int off = 1; off < 32; off <<= 1) sum += __shfl_xor(sum, off);
    float mu = sum * (1.0f / 256.0f);
    float d[8], vs = 0.f;
#pragma unroll
    for (int c = 0; c < 8; ++c) { d[c] = v[c] - mu; vs = fmaf(d[c], d[c], vs); }
#pragma unroll
    for (int off = 1; off < 32; off <<= 1) vs += __shfl_xor(vs, off);
    float rstd = rsqrtf(vs * (1.0f / 256.0f) + LN_EPS);
    float4 gv0 = *reinterpret_cast<const float4*>(lng + c0);
    float4 gv1 = *reinterpret_cast<const float4*>(lng + c0 + 4);
    float4 bb0 = *reinterpret_cast<const float4*>(lnb + c0);
    float4 bb1 = *reinterpret_cast<const float4*>(lnb + c0 + 4);
    float g[8] = {gv0.x, gv0.y, gv0.z, gv0.w, gv1.x, gv1.y, gv1.z, gv1.w};
    float bbv[8] = {bb0.x, bb0.y, bb0.z, bb0.w, bb1.x, bb1.y, bb1.z, bb1.w};
    float o[8];
#pragma unroll
    for (int c = 0; c < 8; ++c) {
        float val = fmaf(d[c] * rstd, g[c], bbv[c]);
        o[c] = (val > 0.f) ? val : (__expf(val) - 1.0f);
    }

    if (FUSE_W2) {
        float4 wv0 = *reinterpret_cast<const float4*>(W2 + c0);
        float4 wv1 = *reinterpret_cast<const float4*>(W2 + c0 + 4);
        float wv[8] = {wv0.x, wv0.y, wv0.z, wv0.w, wv1.x, wv1.y, wv1.z, wv1.w};
        float p = 0.f;
#pragma unroll
        for (int c = 0; c < 8; ++c) p = fmaf(o[c], wv[c], p);
#pragma unroll
        for (int off = 1; off < 32; off <<= 1) p += __shfl_xor(p, off);
        if (lh == 0) h2[n] = p;
    } else {
        ushort yo[8];
#pragma unroll
        for (int c = 0; c < 8; ++c) yo[c] = f2bf(o[c]);
        *reinterpret_cast<uint4*>(Y + (size_t)n * 256 + c0) =
            *reinterpret_cast<const uint4*>(yo);
    }
}

// ---------------- layer 2 aggregation (H=1,C=1): 4 nodes/wave ----------------

__global__ __launch_bounds__(256) void k_agg2(
    const int* __restrict__ offs, const int* __restrict__ csr,
    const float* __restrict__ h2,
    const float* __restrict__ as2, const float* __restrict__ ad2,
    const float* __restrict__ b2, float* __restrict__ out, int N)
{
    const int tid = threadIdx.x;
    const int wid = tid >> 6;
    const int lane = tid & 63;
    const int quarter = lane >> 4;
    const int lq = lane & 15;
    const int n = blockIdx.x * 16 + wid * 4 + quarter;
    if (n >= N) return;
    const float asv = as2[0], adv = ad2[0];
    const float tval = adv * h2[n];
    const int beg = offs[n], end = offs[n + 1];

    float m = -1e30f, den = 0.f, num = 0.f;
    for (int i = beg + lq; i < end; i += 16) {
        float hv = h2[csr[i]];
        float e = fmaf(asv, hv, tval);
        e = fmaxf(e, NEG_SLOPE * e);
        float nm = fmaxf(m, e);
        float sc = __expf(m - nm);
        float p = __expf(e - nm);
        den = den * sc + p;
        num = fmaf(num, sc, p * hv);
        m = nm;
    }
#pragma unroll
    for (int o = 1; o < 16; o <<= 1) {
        float m2 = __shfl_xor(m, o);
        float d2 = __shfl_xor(den, o);
        float n2 = __shfl_xor(num, o);
        float nm = fmaxf(m, m2);
        float sA = __expf(m - nm);
        float sB = __expf(m2 - nm);
        den = den * sA + d2 * sB;
        num = num * sA + n2 * sB;
        m = nm;
    }
    if (lq == 0) out[n] = num / den + b2[0];
}

// ---------------- launch ----------------

extern "C" void kernel_launch(void* const* d_in, const int* in_sizes, int n_in,
                              void* d_out, int out_size, void* d_ws, size_t ws_size,
                              hipStream_t stream) {
    const float* x   = (const float*)d_in[0];
    const int*   ei  = (const int*)d_in[1];
    const float* W0  = (const float*)d_in[2];
    const float* as0 = (const float*)d_in[3];
    const float* ad0 = (const float*)d_in[4];
    const float* b0  = (const float*)d_in[5];
    const float* W1  = (const float*)d_in[6];
    const float* as1 = (const float*)d_in[7];
    const float* ad1 = (const float*)d_in[8];
    const float* b1  = (const float*)d_in[9];
    const float* W2  = (const float*)d_in[10];
    const float* as2 = (const float*)d_in[11];
    const float* ad2 = (const float*)d_in[12];
    const float* b2  = (const float*)d_in[13];
    const float* lng = (const float*)d_in[14];
    const float* lnb = (const float*)d_in[15];

    const int N = in_sizes[0] / 64;
    const int E = in_sizes[1] / 2;
    const int TOT = E + N;
    const int NBW = (N + 255) / 256;         // 256-node windows (<= 256)
    const int NBC = (TOT + 1023) / 1024;     // count/bin blocks

    char* w = (char*)d_ws;
    auto alloc = [&](size_t bytes) -> void* {
        void* p = (void*)w;
        w += (bytes + 255) & ~(size_t)255;
        return p;
    };
    int*    offs   = (int*)alloc(sizeof(int) * (N + 1));
    int*    csr    = (int*)alloc(sizeof(int) * TOT);
    int*    bcnts  = (int*)alloc(sizeof(int) * (size_t)NBC * 256);
    int*    wtot   = (int*)alloc(sizeof(int) * 256);
    int*    wbase  = (int*)alloc(sizeof(int) * 256);
    unsigned long long* tmp = (unsigned long long*)alloc(sizeof(unsigned long long) * TOT);
    float*  sbuf   = (float*)alloc(sizeof(float) * N * 4);
    float*  tbuf   = (float*)alloc(sizeof(float) * N * 4);
    ushort* Xb     = (ushort*)alloc(sizeof(ushort) * (size_t)N * 64);
    ushort* Wt0    = (ushort*)alloc(sizeof(ushort) * 256 * 64);
    ushort* Wt1    = (ushort*)alloc(sizeof(ushort) * 256 * 256);
    uchar*  hq     = (uchar*)alloc(sizeof(uchar) * (size_t)N * 256);
    ushort* Yb     = (ushort*)alloc(sizeof(ushort) * (size_t)N * 256);
    float*  h2     = (float*)alloc(sizeof(float) * N);
    float*  out    = (float*)d_out;

    // dtype conversions
    const int pre_tot = N * 8 + 64 * 256 + 256 * 256;
    k_pre<<<(pre_tot + 255) / 256, 256, 0, stream>>>(x, W0, W1, Xb, Wt0, Wt1, N);

    // CSR build: per-block counts -> scans -> binned scatter -> window CSR
    k_cnt<<<NBC, 1024, 0, stream>>>(ei, E, N, bcnts);
    k_scanA<<<NBW, 256, 0, stream>>>(bcnts, NBC, wtot);
    k_scanB<<<1, 256, 0, stream>>>(wtot, wbase, NBW);
    k_binA<<<NBC, 1024, 0, stream>>>(ei, E, N, bcnts, wbase, tmp);
    k_win<<<NBW, 256, 0, stream>>>(tmp, wbase, wtot, NBW, N, offs, csr);

    // GEMM grid: 8 xcds x cpx chunks x 4 slices; each block does rbpc row-blocks
    const int nrb = (N + 63) / 64;
    const int cpx = 25;
    const int chunks = 8 * cpx;
    const int rbpc = (nrb + chunks - 1) / chunks;
    const int gemm_grid = chunks * 4;
    const int node_grid8 = (N + 7) / 8;
    const int node_grid16 = (N + 15) / 16;

    // layer 0
    k_gemm_mfma<64><<<gemm_grid, 256, 0, stream>>>(Xb, Wt0, as0, ad0, hq, sbuf, tbuf,
                                                   N, nrb, cpx, rbpc);
    k_agg_ln_elu<false><<<node_grid8, 256, 0, stream>>>(offs, csr, sbuf, tbuf, hq,
                                                        b0, lng, lnb, Yb, nullptr, nullptr, N);
    // layer 1 (+ fused 256->1 projection)
    k_gemm_mfma<256><<<gemm_grid, 256, 0, stream>>>(Yb, Wt1, as1, ad1, hq, sbuf, tbuf,
                                                    N, nrb, cpx, rbpc);
    k_agg_ln_elu<true><<<node_grid8, 256, 0, stream>>>(offs, csr, sbuf, tbuf, hq,
                                                       b1, lng, lnb, nullptr, W2, h2, N);
    // layer 2
    k_agg2<<<node_grid16, 256, 0, stream>>>(offs, csr, h2, as2, ad2, b2, out, N);
}